// Round 9
// baseline (392.830 us; speedup 1.0000x reference)
//
#include <hip/hip_runtime.h>
#include <hip/hip_bf16.h>
#include <stdint.h>
#include <stddef.h>

#define T_STEPS 28
#define I_DIM 28
#define H_DIM 64
#define O_DIM 10
#define BT 32    // batch rows per block
#define NTHREADS 256   // 4 waves: small barrier group

typedef short bf16x8  __attribute__((ext_vector_type(8)));
typedef float f32x4   __attribute__((ext_vector_type(4)));

// exp2 scale constants folded into weights:
//   sigmoid(z) = rcp(1 + exp2(-log2e * z))      -> scale i,f,o rows by KS
//   tanh(z)    = 1 - 2*rcp(1 + exp2(2*log2e*z)) -> scale g rows by KG
#define KS (-1.4426950408889634f)
#define KG ( 2.8853900817779268f)

__device__ __forceinline__ short f2bf(float f){
    uint32_t u = __builtin_bit_cast(uint32_t, f);
    u = (u + 0x7fffu + ((u >> 16) & 1u)) >> 16;
    return (short)u;
}
__device__ __forceinline__ float bf2f(short v){
    return __builtin_bit_cast(float, (uint32_t)(uint16_t)v << 16);
}
// packed f32x2 -> bf16x2 (RNE) as raw bits
__device__ __forceinline__ uint32_t pack_bf16x2(float lo, float hi){
    float2 p2; p2.x = lo; p2.y = hi;
    __hip_bfloat162 p = __float22bfloat162_rn(p2);
    uint32_t u;
    __builtin_memcpy(&u, &p, 4);
    return u;
}

// LDS layout (bytes), BT=32:
//   x0: short[32][40] @ 0      (2560)
//   x1: short[32][40] @ 2560   (2560)
//   h0: short[32][72] @ 5120   (4608)
//   h1: short[32][72] @ 9728   (4608)
//   wout_t: float[640] @ 14336 (2560)
//   bout_s: float[12]  @ 16896 (48)
// stride 72 shorts = 144 B keeps every row 16B-aligned -> ds_read_b128.
#define X_OFF(b)  ((b) * 2560)
#define H_OFF(b)  (5120 + (b) * 4608)
#define SMEM_BYTES (16896 + 48)

__global__ __launch_bounds__(NTHREADS, 4)
void lstm_fused(const float* __restrict__ x,
                const float* __restrict__ W_ih,
                const float* __restrict__ W_hh,
                const float* __restrict__ b_ih,
                const float* __restrict__ b_hh,
                const float* __restrict__ W_out,
                const float* __restrict__ b_out,
                float* __restrict__ out)
{
    __shared__ alignas(16) unsigned char smem[SMEM_BYTES];
    float* wout_t = (float*)(smem + 14336);
    float* bout_s = (float*)(smem + 16896);

    const int tid    = threadIdx.x;
    const int w      = tid >> 6;      // wave 0..3
    const int jgroup = w;             // hidden-col tile: j in [16*jgroup, 16*jgroup+16)
    const int lane = tid & 63;
    const int col  = lane & 15;
    const int quad = lane >> 4;
    const int jcol = jgroup * 16 + col;
    const int b0   = blockIdx.x * BT;

    // ---- weight B-fragments in registers, pre-scaled by exp2 constants ----
    // B[k][n]: lane holds n = nt*64 + jgroup*16 + col, k = quad*8 + j
    // Bias folded into wih row k == I_DIM (x pad col 28 is constant 1.0).
    bf16x8 wih[4];
    bf16x8 whh[2][4];
    #pragma unroll
    for (int nt = 0; nt < 4; ++nt){
        const float sc = (nt == 2) ? KG : KS;
        const int n = nt * 64 + jgroup * 16 + col;
        #pragma unroll
        for (int j = 0; j < 8; ++j){
            const int k = quad * 8 + j;
            wih[nt][j] = (k < I_DIM) ? f2bf(sc * W_ih[n * I_DIM + k])
                       : (k == I_DIM) ? f2bf(sc * (b_ih[n] + b_hh[n]))
                       : (short)0;
        }
        #pragma unroll
        for (int s = 0; s < 2; ++s)
            #pragma unroll
            for (int j = 0; j < 8; ++j){
                const int k = s * 32 + quad * 8 + j;
                whh[s][nt][j] = f2bf(sc * W_hh[n * H_DIM + k]);
            }
    }
    const f32x4 z4 = {0.0f, 0.0f, 0.0f, 0.0f};

    // ---- stage W_out (transposed) + b_out ----
    for (int idx = tid; idx < H_DIM * O_DIM; idx += NTHREADS){
        const int j = idx / O_DIM;
        const int o = idx - j * O_DIM;
        wout_t[idx] = W_out[o * H_DIM + j];
    }
    if (tid < O_DIM) bout_s[tid] = b_out[tid];

    // ---- zero h buffer 0 (initial state) ----
    for (int idx = tid; idx < BT * 72; idx += NTHREADS)
        ((short*)(smem + H_OFF(0)))[idx] = 0;

    // ---- x staging: 8 threads per row, 4 cols each ----
    // col 28 (seg 7, u 0) carries the constant 1.0 that multiplies the folded
    // bias row of wih; cols 29..31 stay 0.
    const int row = tid >> 3;          // 0..31
    const int seg = tid & 7;
    const float* pxs = x + (size_t)(b0 + row) * (T_STEPS * I_DIM) + seg * 4;

    float xa[4];
    #pragma unroll
    for (int u = 0; u < 4; ++u){
        const int c = seg * 4 + u;
        xa[u] = (c < I_DIM) ? pxs[u] : (c == I_DIM ? 1.0f : 0.0f);
    }
    pxs += I_DIM;

    float cst[2][4];
    #pragma unroll
    for (int m = 0; m < 2; ++m)
        #pragma unroll
        for (int r = 0; r < 4; ++r) cst[m][r] = 0.0f;

    for (int t = 0; t < T_STEPS; ++t){
        short (*xb)[40] = (short(*)[40])(smem + X_OFF(t & 1));
        // stage x(t): packed cvt + one b64 LDS store
        {
            uint2 v;
            v.x = pack_bf16x2(xa[0], xa[1]);
            v.y = pack_bf16x2(xa[2], xa[3]);
            *(uint2*)&xb[row][seg * 4] = v;
        }
        __syncthreads();   // single barrier per step; no vmcnt pending here

        // prefetch x(t+1) AFTER the barrier
        if (t < T_STEPS - 1){
            #pragma unroll
            for (int u = 0; u < 4; ++u)
                if (seg * 4 + u < I_DIM) xa[u] = pxs[u];
            pxs += I_DIM;
        }

        const short (*hr)[72] = (const short(*)[72])(smem + H_OFF(t & 1));
        short (*hw)[72]       = (short(*)[72])(smem + H_OFF((t + 1) & 1));

        #pragma unroll
        for (int m = 0; m < 2; ++m){
            const int mt = m;

            // x-projection (bias rides in wih k=28 against x pad col = 1.0)
            f32x4 acc[4];
            {
                bf16x8 a = *(const bf16x8*)&xb[mt * 16 + col][quad * 8];
                #pragma unroll
                for (int nt = 0; nt < 4; ++nt)
                    acc[nt] = __builtin_amdgcn_mfma_f32_16x16x32_bf16(a, wih[nt], z4, 0, 0, 0);
            }
            // recurrence
            #pragma unroll
            for (int s = 0; s < 2; ++s){
                bf16x8 a = *(const bf16x8*)&hr[mt * 16 + col][s * 32 + quad * 8];
                #pragma unroll
                for (int nt = 0; nt < 4; ++nt)
                    acc[nt] = __builtin_amdgcn_mfma_f32_16x16x32_bf16(a, whh[s][nt], acc[nt], 0, 0, 0);
            }

            // activations: 8-WAY reciprocal merge -- ONE v_rcp serves all 8 gate
            // denominators of the row pair (i,f,g,o x 2 rows), reconstructed by
            // multiplication:
            //   P_r = (dA*dB)*(dG*dO);  R = rcp(P0*P1)
            //   1/pAB_0 = R*P1*pGO0 ; 1/pGO_0 = R*P1*pAB0 ; (row1 symmetric)
            //   sigmoid = (1/pXY)*other_denominator ; tanh_g = 1-2*(1/pGO)*dO
            // tanh(c) stays 2-way paired (R5), proven safe bounds.
            // Trans/elem: 5 exp2 + 1 rcp (was 5 + 2.5).
            // Overflow: needs sum of gate-exponents > 128 (~15-sigma); impossible
            // for these distributions. Reconstruction error ~4e-7 << bf16 4e-3.
            float hv[4];
            #pragma unroll
            for (int p = 0; p < 2; ++p){
                const int r0 = 2 * p, r1 = 2 * p + 1;
                const float dA0 = 1.0f + __builtin_amdgcn_exp2f(acc[0][r0]);
                const float dA1 = 1.0f + __builtin_amdgcn_exp2f(acc[0][r1]);
                const float dB0 = 1.0f + __builtin_amdgcn_exp2f(acc[1][r0]);
                const float dB1 = 1.0f + __builtin_amdgcn_exp2f(acc[1][r1]);
                const float dG0 = 1.0f + __builtin_amdgcn_exp2f(acc[2][r0]);
                const float dG1 = 1.0f + __builtin_amdgcn_exp2f(acc[2][r1]);
                const float dO0 = 1.0f + __builtin_amdgcn_exp2f(acc[3][r0]);
                const float dO1 = 1.0f + __builtin_amdgcn_exp2f(acc[3][r1]);
                const float pAB0 = dA0 * dB0, pGO0 = dG0 * dO0;
                const float pAB1 = dA1 * dB1, pGO1 = dG1 * dO1;
                const float P0 = pAB0 * pGO0;
                const float P1 = pAB1 * pGO1;
                const float R  = __builtin_amdgcn_rcpf(P0 * P1);
                const float RP0 = R * P1;          // = 1/P0
                const float RP1 = R * P0;          // = 1/P1
                const float invAB0 = RP0 * pGO0, invGO0 = RP0 * pAB0;
                const float invAB1 = RP1 * pGO1, invGO1 = RP1 * pAB1;
                const float iv0 = invAB0 * dB0, fv0 = invAB0 * dA0;
                const float iv1 = invAB1 * dB1, fv1 = invAB1 * dA1;
                const float ov0 = invGO0 * dG0, ov1 = invGO1 * dG1;
                const float gv0 = 1.0f - 2.0f * (invGO0 * dO0);
                const float gv1 = 1.0f - 2.0f * (invGO1 * dO1);
                const float c0 = fv0 * cst[m][r0] + iv0 * gv0;
                const float c1 = fv1 * cst[m][r1] + iv1 * gv1;
                cst[m][r0] = c0; cst[m][r1] = c1;
                const float d50 = 1.0f + __builtin_amdgcn_exp2f(KG * c0);
                const float d51 = 1.0f + __builtin_amdgcn_exp2f(KG * c1);
                const float R5 = __builtin_amdgcn_rcpf(d50 * d51);
                const float t2 = 2.0f * R5;
                hv[r0] = ov0 * (1.0f - t2 * d51);
                hv[r1] = ov1 * (1.0f - t2 * d50);
            }
            // packed conversion, two b16 stores per pair (rows differ by 1)
            #pragma unroll
            for (int rp = 0; rp < 2; ++rp){
                uint32_t u = pack_bf16x2(hv[2 * rp], hv[2 * rp + 1]);
                hw[mt * 16 + quad * 4 + 2 * rp    ][jcol] = (short)(u & 0xffffu);
                hw[mt * 16 + quad * 4 + 2 * rp + 1][jcol] = (short)(u >> 16);
            }
        }
    }
    __syncthreads();

    // ---- output projection from final h (bf16, in h buffer 0) ----
    const short (*hfin)[72] = (const short(*)[72])(smem + H_OFF(0));
    for (int idx = tid; idx < BT * O_DIM; idx += NTHREADS){
        const int m = idx / O_DIM;
        const int o = idx - m * O_DIM;
        float s = bout_s[o];
        #pragma unroll 8
        for (int j = 0; j < H_DIM; ++j)
            s += bf2f(hfin[m][j]) * wout_t[j * O_DIM + o];
        out[(size_t)b0 * O_DIM + idx] = s;
    }
}

extern "C" void kernel_launch(void* const* d_in, const int* in_sizes, int n_in,
                              void* d_out, int out_size, void* d_ws, size_t ws_size,
                              hipStream_t stream) {
    const float* x     = (const float*)d_in[0];
    const float* W_ih  = (const float*)d_in[1];
    const float* W_hh  = (const float*)d_in[2];
    const float* b_ih  = (const float*)d_in[3];
    const float* b_hh  = (const float*)d_in[4];
    const float* W_out = (const float*)d_in[5];
    const float* b_out = (const float*)d_in[6];
    float* out = (float*)d_out;

    const int grid = 65536 / BT;   // 2048 blocks x 256 threads
    lstm_fused<<<grid, NTHREADS, 0, stream>>>(x, W_ih, W_hh, b_ih, b_hh, W_out, b_out, out);
}

// Round 10
// 390.883 us; speedup vs baseline: 1.0050x; 1.0050x over previous
//
#include <hip/hip_runtime.h>
#include <hip/hip_bf16.h>
#include <stdint.h>
#include <stddef.h>

#define T_STEPS 28
#define I_DIM 28
#define H_DIM 64
#define O_DIM 10
#define BT 32    // batch rows per block
#define NTHREADS 256   // 4 waves

typedef short bf16x8  __attribute__((ext_vector_type(8)));
typedef float f32x4   __attribute__((ext_vector_type(4)));

// exp2 scale constants folded into weights:
//   sigmoid(z) = rcp(1 + exp2(-log2e * z))      -> scale i,f,o rows by KS
//   tanh(z)    = 1 - 2*rcp(1 + exp2(2*log2e*z)) -> scale g rows by KG
#define KS (-1.4426950408889634f)
#define KG ( 2.8853900817779268f)

__device__ __forceinline__ short f2bf(float f){
    uint32_t u = __builtin_bit_cast(uint32_t, f);
    u = (u + 0x7fffu + ((u >> 16) & 1u)) >> 16;
    return (short)u;
}
__device__ __forceinline__ float bf2f(short v){
    return __builtin_bit_cast(float, (uint32_t)(uint16_t)v << 16);
}
// packed f32x2 -> bf16x2 (RNE) as raw bits
__device__ __forceinline__ uint32_t pack_bf16x2(float lo, float hi){
    float2 p2; p2.x = lo; p2.y = hi;
    __hip_bfloat162 p = __float22bfloat162_rn(p2);
    uint32_t u;
    __builtin_memcpy(&u, &p, 4);
    return u;
}

// LDS layout (bytes), BT=32:
//   x0: short[32][40] @ 0      (2560)
//   x1: short[32][40] @ 2560   (2560)
//   h0: short[32][72] @ 5120   (4608)
//   h1: short[32][72] @ 9728   (4608)
//   wout_t: float[640] @ 14336 (2560)
//   bout_s: float[12]  @ 16896 (48)
// stride 72 shorts = 144 B keeps every row 16B-aligned -> ds_read_b128.
#define X_OFF(b)  ((b) * 2560)
#define H_OFF(b)  (5120 + (b) * 4608)
#define SMEM_BYTES (16896 + 48)

__global__ __launch_bounds__(NTHREADS, 4)
void lstm_fused(const float* __restrict__ x,
                const float* __restrict__ W_ih,
                const float* __restrict__ W_hh,
                const float* __restrict__ b_ih,
                const float* __restrict__ b_hh,
                const float* __restrict__ W_out,
                const float* __restrict__ b_out,
                float* __restrict__ out)
{
    __shared__ alignas(16) unsigned char smem[SMEM_BYTES];
    float* wout_t = (float*)(smem + 14336);
    float* bout_s = (float*)(smem + 16896);

    const int tid    = threadIdx.x;
    const int w      = tid >> 6;      // wave 0..3
    const int jgroup = w;             // hidden-col tile: j in [16*jgroup, 16*jgroup+16)
    const int lane = tid & 63;
    const int col  = lane & 15;
    const int quad = lane >> 4;
    const int jcol = jgroup * 16 + col;
    const int b0   = blockIdx.x * BT;

    // ---- weight B-fragments in registers, pre-scaled by exp2 constants ----
    // B[k][n]: lane holds n = nt*64 + jgroup*16 + col, k = quad*8 + j
    // Bias folded into wih row k == I_DIM (x pad col 28 is constant 1.0).
    bf16x8 wih[4];
    bf16x8 whh[2][4];
    #pragma unroll
    for (int nt = 0; nt < 4; ++nt){
        const float sc = (nt == 2) ? KG : KS;
        const int n = nt * 64 + jgroup * 16 + col;
        #pragma unroll
        for (int j = 0; j < 8; ++j){
            const int k = quad * 8 + j;
            wih[nt][j] = (k < I_DIM) ? f2bf(sc * W_ih[n * I_DIM + k])
                       : (k == I_DIM) ? f2bf(sc * (b_ih[n] + b_hh[n]))
                       : (short)0;
        }
        #pragma unroll
        for (int s = 0; s < 2; ++s)
            #pragma unroll
            for (int j = 0; j < 8; ++j){
                const int k = s * 32 + quad * 8 + j;
                whh[s][nt][j] = f2bf(sc * W_hh[n * H_DIM + k]);
            }
    }
    const f32x4 z4 = {0.0f, 0.0f, 0.0f, 0.0f};

    // ---- stage W_out (transposed) + b_out ----
    for (int idx = tid; idx < H_DIM * O_DIM; idx += NTHREADS){
        const int j = idx / O_DIM;
        const int o = idx - j * O_DIM;
        wout_t[idx] = W_out[o * H_DIM + j];
    }
    if (tid < O_DIM) bout_s[tid] = b_out[tid];

    // ---- zero h buffer 0 (initial state) ----
    for (int idx = tid; idx < BT * 72; idx += NTHREADS)
        ((short*)(smem + H_OFF(0)))[idx] = 0;

    // ---- x staging: 8 threads per row, 4 cols each ----
    // col 28 (seg 7, u 0) carries the constant 1.0 that multiplies the folded
    // bias row of wih; cols 29..31 stay 0. seg 7 never reloads.
    const int row = tid >> 3;          // 0..31
    const int seg = tid & 7;
    const float* pxs = x + (size_t)(b0 + row) * (T_STEPS * I_DIM) + seg * 4;

    float xa[4];
    #pragma unroll
    for (int u = 0; u < 4; ++u){
        const int c = seg * 4 + u;
        xa[u] = (c < I_DIM) ? pxs[u] : (c == I_DIM ? 1.0f : 0.0f);
    }
    pxs += I_DIM;

    float cst[2][4];
    #pragma unroll
    for (int m = 0; m < 2; ++m)
        #pragma unroll
        for (int r = 0; r < 4; ++r) cst[m][r] = 0.0f;

    // static ping-pong buffers: all LDS addresses loop-invariant (hoisted once)
    short (*xb0)[40] = (short(*)[40])(smem + X_OFF(0));
    short (*xb1)[40] = (short(*)[40])(smem + X_OFF(1));
    short (*h0)[72]  = (short(*)[72])(smem + H_OFF(0));
    short (*h1)[72]  = (short(*)[72])(smem + H_OFF(1));

    // One LSTM step: stage x into XB, read h from HR, write h into HW.
    // pf: prefetch next x (uniform bool).
#define LSTM_STEP(XB, HR, HW, pf)                                              \
    {                                                                          \
        {                                                                      \
            uint2 v;                                                           \
            v.x = pack_bf16x2(xa[0], xa[1]);                                   \
            v.y = pack_bf16x2(xa[2], xa[3]);                                   \
            *(uint2*)&(XB)[row][seg * 4] = v;                                  \
        }                                                                      \
        __syncthreads();                                                       \
        if ((pf) && seg < 7){                                                  \
            float4 v = *(const float4*)pxs;                                    \
            xa[0] = v.x; xa[1] = v.y; xa[2] = v.z; xa[3] = v.w;                \
            pxs += I_DIM;                                                      \
        }                                                                      \
        _Pragma("unroll")                                                      \
        for (int m = 0; m < 2; ++m){                                           \
            const int mt = m;                                                  \
            f32x4 acc[4];                                                      \
            {                                                                  \
                bf16x8 a = *(const bf16x8*)&(XB)[mt * 16 + col][quad * 8];     \
                _Pragma("unroll")                                              \
                for (int nt = 0; nt < 4; ++nt)                                 \
                    acc[nt] = __builtin_amdgcn_mfma_f32_16x16x32_bf16(a, wih[nt], z4, 0, 0, 0); \
            }                                                                  \
            _Pragma("unroll")                                                  \
            for (int s = 0; s < 2; ++s){                                       \
                bf16x8 a = *(const bf16x8*)&(HR)[mt * 16 + col][s * 32 + quad * 8]; \
                _Pragma("unroll")                                              \
                for (int nt = 0; nt < 4; ++nt)                                 \
                    acc[nt] = __builtin_amdgcn_mfma_f32_16x16x32_bf16(a, whh[s][nt], acc[nt], 0, 0, 0); \
            }                                                                  \
            float hv[4];                                                       \
            _Pragma("unroll")                                                  \
            for (int p = 0; p < 2; ++p){                                       \
                const int r0 = 2 * p, r1 = 2 * p + 1;                          \
                const float dA0 = 1.0f + __builtin_amdgcn_exp2f(acc[0][r0]);   \
                const float dA1 = 1.0f + __builtin_amdgcn_exp2f(acc[0][r1]);   \
                const float dB0 = 1.0f + __builtin_amdgcn_exp2f(acc[1][r0]);   \
                const float dB1 = 1.0f + __builtin_amdgcn_exp2f(acc[1][r1]);   \
                const float R10 = __builtin_amdgcn_rcpf(dA0 * dB0);            \
                const float R11 = __builtin_amdgcn_rcpf(dA1 * dB1);            \
                const float iv0 = R10 * dB0, fv0 = R10 * dA0;                  \
                const float iv1 = R11 * dB1, fv1 = R11 * dA1;                  \
                const float dG0 = 1.0f + __builtin_amdgcn_exp2f(acc[2][r0]);   \
                const float dG1 = 1.0f + __builtin_amdgcn_exp2f(acc[2][r1]);   \
                const float dO0 = 1.0f + __builtin_amdgcn_exp2f(acc[3][r0]);   \
                const float dO1 = 1.0f + __builtin_amdgcn_exp2f(acc[3][r1]);   \
                const float R20 = __builtin_amdgcn_rcpf(dG0 * dO0);            \
                const float R21 = __builtin_amdgcn_rcpf(dG1 * dO1);            \
                const float ov0 = R20 * dG0, ov1 = R21 * dG1;                  \
                const float gv0 = 1.0f - 2.0f * (R20 * dO0);                   \
                const float gv1 = 1.0f - 2.0f * (R21 * dO1);                   \
                const float c0 = fv0 * cst[m][r0] + iv0 * gv0;                 \
                const float c1 = fv1 * cst[m][r1] + iv1 * gv1;                 \
                cst[m][r0] = c0; cst[m][r1] = c1;                              \
                const float d50 = 1.0f + __builtin_amdgcn_exp2f(KG * c0);      \
                const float d51 = 1.0f + __builtin_amdgcn_exp2f(KG * c1);      \
                const float R5 = __builtin_amdgcn_rcpf(d50 * d51);             \
                const float t2 = 2.0f * R5;                                    \
                hv[r0] = ov0 * (1.0f - t2 * d51);                              \
                hv[r1] = ov1 * (1.0f - t2 * d50);                              \
            }                                                                  \
            _Pragma("unroll")                                                  \
            for (int rp = 0; rp < 2; ++rp){                                    \
                uint32_t u = pack_bf16x2(hv[2 * rp], hv[2 * rp + 1]);          \
                (HW)[mt * 16 + quad * 4 + 2 * rp    ][jcol] = (short)(u & 0xffffu); \
                (HW)[mt * 16 + quad * 4 + 2 * rp + 1][jcol] = (short)(u >> 16);     \
            }                                                                  \
        }                                                                      \
    }

    // 28 steps = 14 unrolled pairs; even step: xb0,h0->h1; odd: xb1,h1->h0.
    // Final h (t=28) lands in h0, matching the epilogue.
    for (int k = 0; k < 14; ++k){
        LSTM_STEP(xb0, h0, h1, true);
        LSTM_STEP(xb1, h1, h0, (k < 13));
    }
#undef LSTM_STEP

    __syncthreads();

    // ---- output projection from final h (bf16, in h buffer 0) ----
    const short (*hfin)[72] = (const short(*)[72])(smem + H_OFF(0));
    for (int idx = tid; idx < BT * O_DIM; idx += NTHREADS){
        const int m = idx / O_DIM;
        const int o = idx - m * O_DIM;
        float s = bout_s[o];
        #pragma unroll 8
        for (int j = 0; j < H_DIM; ++j)
            s += bf2f(hfin[m][j]) * wout_t[j * O_DIM + o];
        out[(size_t)b0 * O_DIM + idx] = s;
    }
}

extern "C" void kernel_launch(void* const* d_in, const int* in_sizes, int n_in,
                              void* d_out, int out_size, void* d_ws, size_t ws_size,
                              hipStream_t stream) {
    const float* x     = (const float*)d_in[0];
    const float* W_ih  = (const float*)d_in[1];
    const float* W_hh  = (const float*)d_in[2];
    const float* b_ih  = (const float*)d_in[3];
    const float* b_hh  = (const float*)d_in[4];
    const float* W_out = (const float*)d_in[5];
    const float* b_out = (const float*)d_in[6];
    float* out = (float*)d_out;

    const int grid = 65536 / BT;   // 2048 blocks x 256 threads
    lstm_fused<<<grid, NTHREADS, 0, stream>>>(x, W_ih, W_hh, b_ih, b_hh, W_out, b_out, out);
}